// Round 8
// baseline (407.733 us; speedup 1.0000x reference)
//
#include <hip/hip_runtime.h>
#include <hip/hip_bf16.h>
#include <cstdint>

#define D_MODEL 1024
#define HEAD    64
#define SEQ     4096
#define BATCH   4
#define NROWS   (BATCH * SEQ)   // 16384

typedef __attribute__((ext_vector_type(8))) short short8;   // 8 bf16 (MFMA A/B frag)
typedef __attribute__((ext_vector_type(4))) float floatx4;  // MFMA C/D frag

__device__ __forceinline__ ushort f2bf(float f) {
    union { __hip_bfloat16 h; ushort u; } c;
    c.h = __float2bfloat16(f);
    return c.u;
}
__device__ __forceinline__ uint pk2(float a, float b) {
    return (uint)f2bf(a) | ((uint)f2bf(b) << 16);
}

// Async global->LDS, 16B per lane, wave-uniform LDS base (+lane*16 implicit).
__device__ __forceinline__ void gload16(const void* g, void* l) {
    __builtin_amdgcn_global_load_lds(
        (const __attribute__((address_space(1))) unsigned int*)g,
        (__attribute__((address_space(3))) unsigned int*)l, 16, 0, 0);
}

// ---------------------------------------------------------------------------
// wt[which][n][k] = w_which[k][n] bf16, via LDS tile transpose (coalesced both ways).
// Grid (D_MODEL/64, 3), 256 threads.
__global__ __launch_bounds__(256) void wprep_kernel(
    const float* __restrict__ wq, const float* __restrict__ wk,
    const float* __restrict__ wv, ushort* __restrict__ wt)
{
    const int which = blockIdx.y;
    const int k0    = blockIdx.x * 64;
    const float* w  = (which == 0) ? wq : (which == 1) ? wk : wv;
    const int tid   = threadIdx.x;

    __shared__ ushort lds[64][65];

#pragma unroll
    for (int i = 0; i < 16; ++i) {
        int idx = tid + 256 * i;          // 0..4095
        int kl  = idx >> 6;
        int n   = idx & 63;
        lds[n][kl] = f2bf(w[(size_t)(k0 + kl) * 64 + n]);   // coalesced read
    }
    __syncthreads();
#pragma unroll
    for (int i = 0; i < 16; ++i) {
        int idx = tid + 256 * i;
        int n   = idx >> 6;
        int kl  = idx & 63;
        wt[(size_t)(which * 64 + n) * D_MODEL + k0 + kl] = lds[n][kl];  // coalesced write
    }
}

// ---------------------------------------------------------------------------
// proj (FROZEN, R7 best = 80.0us): R3 async-LDS staging + counted vmcnt(6) +
// raw barriers + setprio. Ledger: reg-dbuf 93, K-split 95, R3 syncthreads 82.7,
// barrier-free counted 89, fat-burst reg-W 96, this 80. Six structures all
// land ~80-96us at ~1.2-1.35 TB/s; floor unexplained -- do not touch further.
__global__ __launch_bounds__(256) void proj_kernel(
    const float* __restrict__ xq, const float* __restrict__ xk,
    const float* __restrict__ xv, const ushort* __restrict__ wt,
    ushort* __restrict__ qh, ushort* __restrict__ kh, ushort* __restrict__ vt)
{
    const int which = blockIdx.y;
    const float*  x = (which == 0) ? xq : (which == 1) ? xk : xv;
    const ushort* w = wt + (size_t)which * 64 * D_MODEL;

    const int row0 = blockIdx.x * 64;
    const int tid  = threadIdx.x;
    const int wv   = tid >> 6;
    const int ln   = tid & 63;
    const int l16  = ln & 15;
    const int quad = ln >> 4;

    __shared__ float  Abuf[2][64 * 64];   // [row][col f32], 256B/row, col-swizzled
    __shared__ ushort Wbuf[2][64 * 64];   // [n][k bf16], 128B/row, col-swizzled

    const float* asrc[4];
#pragma unroll
    for (int i = 0; i < 4; ++i) {
        int j  = wv * 4 + i;
        int lr = 4 * j + (ln >> 4);
        int cf = ((ln & 15) ^ (lr & 15)) * 4;
        asrc[i] = x + (size_t)(row0 + lr) * D_MODEL + cf;
    }
    const ushort* wsrc[2];
#pragma unroll
    for (int i = 0; i < 2; ++i) {
        int j  = wv * 2 + i;
        int n  = 8 * j + (ln >> 3);
        int kc = ((ln & 7) ^ (ln >> 3)) * 8;
        wsrc[i] = w + (size_t)n * D_MODEL + kc;
    }

    floatx4 acc[4] = {};

#define STAGE(buf, kk)                                                        \
    do {                                                                      \
        char* ab_ = (char*)&Abuf[buf][0];                                     \
        char* wb_ = (char*)&Wbuf[buf][0];                                     \
        _Pragma("unroll")                                                     \
        for (int i_ = 0; i_ < 4; ++i_)                                        \
            gload16(asrc[i_] + (kk), ab_ + (wv * 4 + i_) * 1024);             \
        _Pragma("unroll")                                                     \
        for (int i_ = 0; i_ < 2; ++i_)                                        \
            gload16(wsrc[i_] + (kk), wb_ + (wv * 2 + i_) * 1024);             \
    } while (0)

#define COMPUTE(buf)                                                          \
    do {                                                                      \
        const char* ab_ = (const char*)&Abuf[buf][0];                         \
        const char* wb_ = (const char*)&Wbuf[buf][0];                         \
        const int arow_ = wv * 16 + l16;                                      \
        const int akey_ = l16 << 4;            /* (arow&15)<<4 */             \
        _Pragma("unroll")                                                     \
        for (int ks_ = 0; ks_ < 2; ++ks_) {                                   \
            const int colb_ = (ks_ * 32 + quad * 8) * 4;                      \
            float4 f0 = *(const float4*)(ab_ + arow_ * 256 + ((colb_)      ^ akey_)); \
            float4 f1 = *(const float4*)(ab_ + arow_ * 256 + ((colb_ + 16) ^ akey_)); \
            union { short8 s; uint u[4]; } a_;                                \
            a_.u[0] = pk2(f0.x, f0.y); a_.u[1] = pk2(f0.z, f0.w);             \
            a_.u[2] = pk2(f1.x, f1.y); a_.u[3] = pk2(f1.z, f1.w);             \
            const int wcolb_ = (ks_ * 32 + quad * 8) * 2;                     \
            const int wkey_  = (l16 & 7) << 4;  /* (n&7)<<4, n=nt*16+l16 */   \
            _Pragma("unroll")                                                 \
            for (int nt_ = 0; nt_ < 4; ++nt_) {                               \
                const int n_ = nt_ * 16 + l16;                                \
                short8 bf_ = *(const short8*)(wb_ + n_ * 128 + (wcolb_ ^ wkey_)); \
                acc[nt_] = __builtin_amdgcn_mfma_f32_16x16x32_bf16(a_.s, bf_, acc[nt_], 0, 0, 0); \
            }                                                                 \
        }                                                                     \
    } while (0)

    STAGE(0, 0);
    STAGE(1, 64);
    for (int t = 0; t < 16; ++t) {
        if (t == 15) {
            asm volatile("s_waitcnt vmcnt(0)" ::: "memory");
        } else {
            asm volatile("s_waitcnt vmcnt(6)" ::: "memory");
        }
        __builtin_amdgcn_sched_barrier(0);
        __builtin_amdgcn_s_barrier();        // all waves' chunk-t parts landed
        __builtin_amdgcn_sched_barrier(0);
        __builtin_amdgcn_s_setprio(1);
        COMPUTE(t & 1);
        __builtin_amdgcn_s_setprio(0);
        __builtin_amdgcn_sched_barrier(0);
        __builtin_amdgcn_s_barrier();        // all waves done READING buf t&1
        __builtin_amdgcn_sched_barrier(0);
        if (t + 2 < 16) STAGE(t & 1, (t + 2) * 64);
    }
#undef STAGE
#undef COMPUTE

    const int rbase = row0 + wv * 16 + quad * 4;
    if (which < 2) {
        ushort* y = (which == 0) ? qh : kh;
        const float sc = (which == 0) ? 0.125f : 1.0f;   // fold head^-0.5 into qh
#pragma unroll
        for (int nt = 0; nt < 4; ++nt) {
            int h = nt * 16 + l16;
#pragma unroll
            for (int r = 0; r < 4; ++r)
                y[(size_t)(rbase + r) * HEAD + h] = f2bf(acc[nt][r] * sc);
        }
    } else {
        const int b  = rbase >> 12;
        const int s0 = rbase & (SEQ - 1);
#pragma unroll
        for (int nt = 0; nt < 4; ++nt) {
            int h = nt * 16 + l16;
            uint2 pk = make_uint2(pk2(acc[nt][0], acc[nt][1]), pk2(acc[nt][2], acc[nt][3]));
            *(uint2*)&vt[(size_t)(b * 64 + h) * SEQ + s0] = pk;
        }
    }
}

// ---------------------------------------------------------------------------
// MFMA flash attention v3: paired q-tiles (kept -- R6 A/B: pairing beats
// 1-chain TLP) with SIX-wave K-split instead of four. 512 blocks x 6 waves =
// 3072 waves = 3 waves/SIMD (was 2): +50% TLP against the latency-bound
// load->QK->exp->LDS->PV chain, with load-sharing (A/B same key tile) and
// perfect pair balance intact. __launch_bounds__(384,3) caps VGPR at 170 so
// 2 blocks (12 waves) stay resident per CU; LDS 53KB x 2 = 106KB. setprio(1)
// wraps both MFMA clusters (T5: +4-7% on attn, m191).
__global__ __launch_bounds__(384, 3) void attn_kernel(
    const ushort* __restrict__ qh, const ushort* __restrict__ kh,
    const ushort* __restrict__ vt, float* __restrict__ out)
{
    const int b    = blockIdx.x >> 7;          // 4 batches x 128 tile-pairs
    const int i    = blockIdx.x & 127;
    const int qsA  = i, qsB = 255 - i;
    const int q0A  = qsA * 16, q0B = qsB * 16;
    const int nA   = (qsA >> 2) + 1;           // key tiles for tile A
    const int nB   = (qsB >> 2) + 1;
    const int tid  = threadIdx.x;
    const int wv   = tid >> 6;                 // 0..5
    const int ln   = tid & 63;
    const int l16  = ln & 15;
    const int quad = ln >> 4;

    __shared__ ushort PA[6][16 * 72];
    __shared__ ushort PB[6][16 * 72];
    __shared__ float  Obuf[6][16][68];
    __shared__ float  Lbuf[6][16];

    const ushort* khb = kh + (size_t)b * SEQ * HEAD;
    const ushort* vtb = vt + (size_t)b * HEAD * SEQ;

    // Q B-frags (pre-scaled): n = l16 -> qrow, k = quad*8+j -> h
    const size_t qbA = ((size_t)b * SEQ + q0A + l16) * HEAD + quad * 8;
    const size_t qbB = ((size_t)b * SEQ + q0B + l16) * HEAD + quad * 8;
    const short8 qA0 = *(const short8*)(qh + qbA);
    const short8 qA1 = *(const short8*)(qh + qbA + 32);
    const short8 qB0 = *(const short8*)(qh + qbB);
    const short8 qB1 = *(const short8*)(qh + qbB + 32);

    floatx4 OA[4] = {}, OB[4] = {};
    float rsA = 0.f, rsB = 0.f;
    ushort* myPA = PA[wv];
    ushort* myPB = PB[wv];

    const int cA = (nA > wv) ? (((nA - 1 - wv) / 6) + 1) : 0;   // steps for A
    const int cB = (nB > wv) ? (((nB - 1 - wv) / 6) + 1) : 0;   // nB >= 33 > 5
    const int steps = (cA > cB) ? cA : cB;

    for (int s = 0; s < steps; ++s) {
        const int kt = wv + 6 * s;                 // same tile for A and B
        const bool doA = s < cA, doB = s < cB;
        const int k0 = kt * 64;

        short8 kfA[8], vfA[8], kfB[8], vfB[8];
        if (doA) {
#pragma unroll
            for (int nt = 0; nt < 4; ++nt) {
                const ushort* vp = vtb + (size_t)(nt * 16 + l16) * SEQ + k0 + quad * 8;
                vfA[nt * 2] = *(const short8*)vp; vfA[nt * 2 + 1] = *(const short8*)(vp + 32);
                const ushort* kp = khb + (size_t)(k0 + nt * 16 + l16) * HEAD + quad * 8;
                kfA[nt * 2] = *(const short8*)kp; kfA[nt * 2 + 1] = *(const short8*)(kp + 32);
            }
        }
        if (doB) {
#pragma unroll
            for (int nt = 0; nt < 4; ++nt) {
                const ushort* vp = vtb + (size_t)(nt * 16 + l16) * SEQ + k0 + quad * 8;
                vfB[nt * 2] = *(const short8*)vp; vfB[nt * 2 + 1] = *(const short8*)(vp + 32);
                const ushort* kp = khb + (size_t)(k0 + nt * 16 + l16) * HEAD + quad * 8;
                kfB[nt * 2] = *(const short8*)kp; kfB[nt * 2 + 1] = *(const short8*)(kp + 32);
            }
        }

        // S^T = K Q^T : C row = key (quad*4+r), col = qrow (l16)
        floatx4 aA[4], aB[4];
        __builtin_amdgcn_s_setprio(1);
        if (doA) {
#pragma unroll
            for (int nt = 0; nt < 4; ++nt) {
                floatx4 c = {};
                c = __builtin_amdgcn_mfma_f32_16x16x32_bf16(kfA[nt * 2],     qA0, c, 0, 0, 0);
                c = __builtin_amdgcn_mfma_f32_16x16x32_bf16(kfA[nt * 2 + 1], qA1, c, 0, 0, 0);
                aA[nt] = c;
            }
        }
        if (doB) {
#pragma unroll
            for (int nt = 0; nt < 4; ++nt) {
                floatx4 c = {};
                c = __builtin_amdgcn_mfma_f32_16x16x32_bf16(kfB[nt * 2],     qB0, c, 0, 0, 0);
                c = __builtin_amdgcn_mfma_f32_16x16x32_bf16(kfB[nt * 2 + 1], qB1, c, 0, 0, 0);
                aB[nt] = c;
            }
        }
        __builtin_amdgcn_s_setprio(0);

        if (doA) {
            const bool masked = (kt == nA - 1);
#pragma unroll
            for (int nt = 0; nt < 4; ++nt) {
                union { ushort u[4]; uint2 w; } pk;
#pragma unroll
                for (int r = 0; r < 4; ++r) {
                    float sv = aA[nt][r];
                    if (masked && (k0 + nt * 16 + quad * 4 + r > q0A + l16)) sv = -3.0e38f;
                    float p = __expf(sv);
                    rsA += p;
                    pk.u[r] = f2bf(p);
                }
                *(uint2*)&myPA[l16 * 72 + nt * 16 + quad * 4] = pk.w;
            }
        }
        if (doB) {
            const bool masked = (kt == nB - 1);
#pragma unroll
            for (int nt = 0; nt < 4; ++nt) {
                union { ushort u[4]; uint2 w; } pk;
#pragma unroll
                for (int r = 0; r < 4; ++r) {
                    float sv = aB[nt][r];
                    if (masked && (k0 + nt * 16 + quad * 4 + r > q0B + l16)) sv = -3.0e38f;
                    float p = __expf(sv);
                    rsB += p;
                    pk.u[r] = f2bf(p);
                }
                *(uint2*)&myPB[l16 * 72 + nt * 16 + quad * 4] = pk.w;
            }
        }

        __builtin_amdgcn_s_setprio(1);
        if (doA) {
            short8 p0 = *(const short8*)&myPA[l16 * 72 + quad * 8];
            short8 p1 = *(const short8*)&myPA[l16 * 72 + 32 + quad * 8];
#pragma unroll
            for (int nt = 0; nt < 4; ++nt) {
                OA[nt] = __builtin_amdgcn_mfma_f32_16x16x32_bf16(p0, vfA[nt * 2],     OA[nt], 0, 0, 0);
                OA[nt] = __builtin_amdgcn_mfma_f32_16x16x32_bf16(p1, vfA[nt * 2 + 1], OA[nt], 0, 0, 0);
            }
        }
        if (doB) {
            short8 p0 = *(const short8*)&myPB[l16 * 72 + quad * 8];
            short8 p1 = *(const short8*)&myPB[l16 * 72 + 32 + quad * 8];
#pragma unroll
            for (int nt = 0; nt < 4; ++nt) {
                OB[nt] = __builtin_amdgcn_mfma_f32_16x16x32_bf16(p0, vfB[nt * 2],     OB[nt], 0, 0, 0);
                OB[nt] = __builtin_amdgcn_mfma_f32_16x16x32_bf16(p1, vfB[nt * 2 + 1], OB[nt], 0, 0, 0);
            }
        }
        __builtin_amdgcn_s_setprio(0);
    }

    // ---- merge tile A (6 K-split partials, (O,l) additive) ----
    rsA += __shfl_xor(rsA, 16); rsA += __shfl_xor(rsA, 32);
    if (quad == 0) Lbuf[wv][l16] = rsA;
#pragma unroll
    for (int nt = 0; nt < 4; ++nt)
#pragma unroll
        for (int r = 0; r < 4; ++r)
            Obuf[wv][quad * 4 + r][nt * 16 + l16] = OA[nt][r];
    __syncthreads();
    if (tid < 256) {
        const int row = tid >> 4, h0 = (tid & 15) * 4;
        float l = 0.f;
#pragma unroll
        for (int wq_ = 0; wq_ < 6; ++wq_) l += Lbuf[wq_][row];
        float inv = 1.f / l;
        float4 o = make_float4(0.f, 0.f, 0.f, 0.f);
#pragma unroll
        for (int wq_ = 0; wq_ < 6; ++wq_) {
            o.x += Obuf[wq_][row][h0 + 0];
            o.y += Obuf[wq_][row][h0 + 1];
            o.z += Obuf[wq_][row][h0 + 2];
            o.w += Obuf[wq_][row][h0 + 3];
        }
        o.x *= inv; o.y *= inv; o.z *= inv; o.w *= inv;
        *(float4*)&out[((size_t)b * SEQ + q0A + row) * HEAD + h0] = o;
    }
    __syncthreads();

    // ---- merge tile B ----
    rsB += __shfl_xor(rsB, 16); rsB += __shfl_xor(rsB, 32);
    if (quad == 0) Lbuf[wv][l16] = rsB;
#pragma unroll
    for (int nt = 0; nt < 4; ++nt)
#pragma unroll
        for (int r = 0; r < 4; ++r)
            Obuf[wv][quad * 4 + r][nt * 16 + l16] = OB[nt][r];
    __syncthreads();
    if (tid < 256) {
        const int row = tid >> 4, h0 = (tid & 15) * 4;
        float l = 0.f;
#pragma unroll
        for (int wq_ = 0; wq_ < 6; ++wq_) l += Lbuf[wq_][row];
        float inv = 1.f / l;
        float4 o = make_float4(0.f, 0.f, 0.f, 0.f);
#pragma unroll
        for (int wq_ = 0; wq_ < 6; ++wq_) {
            o.x += Obuf[wq_][row][h0 + 0];
            o.y += Obuf[wq_][row][h0 + 1];
            o.z += Obuf[wq_][row][h0 + 2];
            o.w += Obuf[wq_][row][h0 + 3];
        }
        o.x *= inv; o.y *= inv; o.z *= inv; o.w *= inv;
        *(float4*)&out[((size_t)b * SEQ + q0B + row) * HEAD + h0] = o;
    }
}

// ---------------------------------------------------------------------------
extern "C" void kernel_launch(void* const* d_in, const int* in_sizes, int n_in,
                              void* d_out, int out_size, void* d_ws, size_t ws_size,
                              hipStream_t stream) {
    const float* q  = (const float*)d_in[0];
    const float* k  = (const float*)d_in[1];
    const float* v  = (const float*)d_in[2];
    const float* wq = (const float*)d_in[3];
    const float* wk = (const float*)d_in[4];
    const float* wv = (const float*)d_in[5];

    // ws: qh bf16 (2MB) | kh bf16 (2MB) | vt bf16 [4][64][4096] (2MB) | wt (384KB)
    ushort* qh = (ushort*)d_ws;
    ushort* kh = qh + (size_t)NROWS * HEAD;
    ushort* vt = kh + (size_t)NROWS * HEAD;
    ushort* wt = vt + (size_t)NROWS * HEAD;

    dim3 wgrid(D_MODEL / 64, 3);
    wprep_kernel<<<wgrid, 256, 0, stream>>>(wq, wk, wv, wt);

    dim3 pgrid(NROWS / 64, 3);   // 256 x 3, 4-wave blocks, counted-vmcnt staging
    proj_kernel<<<pgrid, 256, 0, stream>>>(q, k, v, wt, qh, kh, vt);

    attn_kernel<<<BATCH * 128, 384, 0, stream>>>(qh, kh, vt, (float*)d_out);
}

// Round 9
// 268.291 us; speedup vs baseline: 1.5197x; 1.5197x over previous
//
#include <hip/hip_runtime.h>
#include <hip/hip_bf16.h>
#include <cstdint>

#define D_MODEL 1024
#define HEAD    64
#define SEQ     4096
#define BATCH   4
#define NROWS   (BATCH * SEQ)   // 16384

typedef __attribute__((ext_vector_type(8))) short short8;   // 8 bf16 (MFMA A/B frag)
typedef __attribute__((ext_vector_type(4))) float floatx4;  // MFMA C/D frag

__device__ __forceinline__ ushort f2bf(float f) {
    union { __hip_bfloat16 h; ushort u; } c;
    c.h = __float2bfloat16(f);
    return c.u;
}
__device__ __forceinline__ uint pk2(float a, float b) {
    return (uint)f2bf(a) | ((uint)f2bf(b) << 16);
}

// Async global->LDS, 16B per lane, wave-uniform LDS base (+lane*16 implicit).
__device__ __forceinline__ void gload16(const void* g, void* l) {
    __builtin_amdgcn_global_load_lds(
        (const __attribute__((address_space(1))) unsigned int*)g,
        (__attribute__((address_space(3))) unsigned int*)l, 16, 0, 0);
}

// ---------------------------------------------------------------------------
// wt[which][n][k] = w_which[k][n] bf16, via LDS tile transpose (coalesced both ways).
// Grid (D_MODEL/64, 3), 256 threads.
__global__ __launch_bounds__(256) void wprep_kernel(
    const float* __restrict__ wq, const float* __restrict__ wk,
    const float* __restrict__ wv, ushort* __restrict__ wt)
{
    const int which = blockIdx.y;
    const int k0    = blockIdx.x * 64;
    const float* w  = (which == 0) ? wq : (which == 1) ? wk : wv;
    const int tid   = threadIdx.x;

    __shared__ ushort lds[64][65];

#pragma unroll
    for (int i = 0; i < 16; ++i) {
        int idx = tid + 256 * i;          // 0..4095
        int kl  = idx >> 6;
        int n   = idx & 63;
        lds[n][kl] = f2bf(w[(size_t)(k0 + kl) * 64 + n]);   // coalesced read
    }
    __syncthreads();
#pragma unroll
    for (int i = 0; i < 16; ++i) {
        int idx = tid + 256 * i;
        int n   = idx >> 6;
        int kl  = idx & 63;
        wt[(size_t)(which * 64 + n) * D_MODEL + k0 + kl] = lds[n][kl];  // coalesced write
    }
}

// ---------------------------------------------------------------------------
// proj (FROZEN, R7 best = 80.0us): R3 async-LDS staging + counted vmcnt(6) +
// raw barriers + setprio. Ledger: reg-dbuf 93, K-split 95, R3 syncthreads 82.7,
// barrier-free counted 89, fat-burst reg-W 96, this 80. Six structures all
// land ~80-96us at ~1.2-1.35 TB/s; floor unexplained -- do not touch further.
__global__ __launch_bounds__(256) void proj_kernel(
    const float* __restrict__ xq, const float* __restrict__ xk,
    const float* __restrict__ xv, const ushort* __restrict__ wt,
    ushort* __restrict__ qh, ushort* __restrict__ kh, ushort* __restrict__ vt)
{
    const int which = blockIdx.y;
    const float*  x = (which == 0) ? xq : (which == 1) ? xk : xv;
    const ushort* w = wt + (size_t)which * 64 * D_MODEL;

    const int row0 = blockIdx.x * 64;
    const int tid  = threadIdx.x;
    const int wv   = tid >> 6;
    const int ln   = tid & 63;
    const int l16  = ln & 15;
    const int quad = ln >> 4;

    __shared__ float  Abuf[2][64 * 64];   // [row][col f32], 256B/row, col-swizzled
    __shared__ ushort Wbuf[2][64 * 64];   // [n][k bf16], 128B/row, col-swizzled

    const float* asrc[4];
#pragma unroll
    for (int i = 0; i < 4; ++i) {
        int j  = wv * 4 + i;
        int lr = 4 * j + (ln >> 4);
        int cf = ((ln & 15) ^ (lr & 15)) * 4;
        asrc[i] = x + (size_t)(row0 + lr) * D_MODEL + cf;
    }
    const ushort* wsrc[2];
#pragma unroll
    for (int i = 0; i < 2; ++i) {
        int j  = wv * 2 + i;
        int n  = 8 * j + (ln >> 3);
        int kc = ((ln & 7) ^ (ln >> 3)) * 8;
        wsrc[i] = w + (size_t)n * D_MODEL + kc;
    }

    floatx4 acc[4] = {};

#define STAGE(buf, kk)                                                        \
    do {                                                                      \
        char* ab_ = (char*)&Abuf[buf][0];                                     \
        char* wb_ = (char*)&Wbuf[buf][0];                                     \
        _Pragma("unroll")                                                     \
        for (int i_ = 0; i_ < 4; ++i_)                                        \
            gload16(asrc[i_] + (kk), ab_ + (wv * 4 + i_) * 1024);             \
        _Pragma("unroll")                                                     \
        for (int i_ = 0; i_ < 2; ++i_)                                        \
            gload16(wsrc[i_] + (kk), wb_ + (wv * 2 + i_) * 1024);             \
    } while (0)

#define COMPUTE(buf)                                                          \
    do {                                                                      \
        const char* ab_ = (const char*)&Abuf[buf][0];                         \
        const char* wb_ = (const char*)&Wbuf[buf][0];                         \
        const int arow_ = wv * 16 + l16;                                      \
        const int akey_ = l16 << 4;            /* (arow&15)<<4 */             \
        _Pragma("unroll")                                                     \
        for (int ks_ = 0; ks_ < 2; ++ks_) {                                   \
            const int colb_ = (ks_ * 32 + quad * 8) * 4;                      \
            float4 f0 = *(const float4*)(ab_ + arow_ * 256 + ((colb_)      ^ akey_)); \
            float4 f1 = *(const float4*)(ab_ + arow_ * 256 + ((colb_ + 16) ^ akey_)); \
            union { short8 s; uint u[4]; } a_;                                \
            a_.u[0] = pk2(f0.x, f0.y); a_.u[1] = pk2(f0.z, f0.w);             \
            a_.u[2] = pk2(f1.x, f1.y); a_.u[3] = pk2(f1.z, f1.w);             \
            const int wcolb_ = (ks_ * 32 + quad * 8) * 2;                     \
            const int wkey_  = (l16 & 7) << 4;  /* (n&7)<<4, n=nt*16+l16 */   \
            _Pragma("unroll")                                                 \
            for (int nt_ = 0; nt_ < 4; ++nt_) {                               \
                const int n_ = nt_ * 16 + l16;                                \
                short8 bf_ = *(const short8*)(wb_ + n_ * 128 + (wcolb_ ^ wkey_)); \
                acc[nt_] = __builtin_amdgcn_mfma_f32_16x16x32_bf16(a_.s, bf_, acc[nt_], 0, 0, 0); \
            }                                                                 \
        }                                                                     \
    } while (0)

    STAGE(0, 0);
    STAGE(1, 64);
    for (int t = 0; t < 16; ++t) {
        if (t == 15) {
            asm volatile("s_waitcnt vmcnt(0)" ::: "memory");
        } else {
            asm volatile("s_waitcnt vmcnt(6)" ::: "memory");
        }
        __builtin_amdgcn_sched_barrier(0);
        __builtin_amdgcn_s_barrier();        // all waves' chunk-t parts landed
        __builtin_amdgcn_sched_barrier(0);
        __builtin_amdgcn_s_setprio(1);
        COMPUTE(t & 1);
        __builtin_amdgcn_s_setprio(0);
        __builtin_amdgcn_sched_barrier(0);
        __builtin_amdgcn_s_barrier();        // all waves done READING buf t&1
        __builtin_amdgcn_sched_barrier(0);
        if (t + 2 < 16) STAGE(t & 1, (t + 2) * 64);
    }
#undef STAGE
#undef COMPUTE

    const int rbase = row0 + wv * 16 + quad * 4;
    if (which < 2) {
        ushort* y = (which == 0) ? qh : kh;
        const float sc = (which == 0) ? 0.125f : 1.0f;   // fold head^-0.5 into qh
#pragma unroll
        for (int nt = 0; nt < 4; ++nt) {
            int h = nt * 16 + l16;
#pragma unroll
            for (int r = 0; r < 4; ++r)
                y[(size_t)(rbase + r) * HEAD + h] = f2bf(acc[nt][r] * sc);
        }
    } else {
        const int b  = rbase >> 12;
        const int s0 = rbase & (SEQ - 1);
#pragma unroll
        for (int nt = 0; nt < 4; ++nt) {
            int h = nt * 16 + l16;
            uint2 pk = make_uint2(pk2(acc[nt][0], acc[nt][1]), pk2(acc[nt][2], acc[nt][3]));
            *(uint2*)&vt[(size_t)(b * 64 + h) * SEQ + s0] = pk;
        }
    }
}

// ---------------------------------------------------------------------------
// MFMA flash attention v4 = R3 paired structure (known-good, no launch-bounds
// cap -- R8's (384,3) cap spilled 418MB to scratch, 208us) + ONE fix:
// the paired tiles A,B process the SAME key tile (ktA==ktB==wv+4s), but R3
// loaded kf/vf TWICE into separate registers under different guards (doA/doB
// prevent compiler CSE). Load ONCE (cA <= cB always, so guard doA||doB) and
// feed both QK^T and both PV chains: halves step load instructions + L2
// traffic, frees ~64 VGPRs. Everything else byte-identical to R3.
__global__ __launch_bounds__(256, 2) void attn_kernel(
    const ushort* __restrict__ qh, const ushort* __restrict__ kh,
    const ushort* __restrict__ vt, float* __restrict__ out)
{
    const int b    = blockIdx.x >> 7;          // 4 batches x 128 tile-pairs
    const int i    = blockIdx.x & 127;
    const int qsA  = i, qsB = 255 - i;
    const int q0A  = qsA * 16, q0B = qsB * 16;
    const int nA   = (qsA >> 2) + 1;           // key tiles for tile A
    const int nB   = (qsB >> 2) + 1;
    const int tid  = threadIdx.x;
    const int wv   = tid >> 6;
    const int ln   = tid & 63;
    const int l16  = ln & 15;
    const int quad = ln >> 4;

    __shared__ ushort PA[4][16 * 72];
    __shared__ ushort PB[4][16 * 72];
    __shared__ float  Obuf[4][16][68];
    __shared__ float  Lbuf[4][16];

    const ushort* khb = kh + (size_t)b * SEQ * HEAD;
    const ushort* vtb = vt + (size_t)b * HEAD * SEQ;

    // Q B-frags (pre-scaled): n = l16 -> qrow, k = quad*8+j -> h
    const size_t qbA = ((size_t)b * SEQ + q0A + l16) * HEAD + quad * 8;
    const size_t qbB = ((size_t)b * SEQ + q0B + l16) * HEAD + quad * 8;
    const short8 qA0 = *(const short8*)(qh + qbA);
    const short8 qA1 = *(const short8*)(qh + qbA + 32);
    const short8 qB0 = *(const short8*)(qh + qbB);
    const short8 qB1 = *(const short8*)(qh + qbB + 32);

    floatx4 OA[4] = {}, OB[4] = {};
    float rsA = 0.f, rsB = 0.f;
    ushort* myPA = PA[wv];
    ushort* myPB = PB[wv];

    const int cA = (nA > wv) ? (((nA - 1 - wv) >> 2) + 1) : 0;   // steps for A
    const int cB = ((nB - 1 - wv) >> 2) + 1;                     // nB >= 33 > wv
    const int steps = (cA > cB) ? cA : cB;                       // == cB (cA<=cB)

    for (int s = 0; s < steps; ++s) {
        const int kt = wv + 4 * s;                 // SAME tile for A and B
        const bool doA = s < cA, doB = s < cB;
        const int k0 = kt * 64;

        // ---- shared K/V fragments (one load feeds both chains) ----
        short8 kf[8], vf[8];
        if (doA || doB) {
#pragma unroll
            for (int nt = 0; nt < 4; ++nt) {
                const ushort* vp = vtb + (size_t)(nt * 16 + l16) * SEQ + k0 + quad * 8;
                vf[nt * 2] = *(const short8*)vp; vf[nt * 2 + 1] = *(const short8*)(vp + 32);
                const ushort* kp = khb + (size_t)(k0 + nt * 16 + l16) * HEAD + quad * 8;
                kf[nt * 2] = *(const short8*)kp; kf[nt * 2 + 1] = *(const short8*)(kp + 32);
            }
        }

        // S^T = K Q^T : C row = key (quad*4+r), col = qrow (l16)
        floatx4 aA[4], aB[4];
        if (doA) {
#pragma unroll
            for (int nt = 0; nt < 4; ++nt) {
                floatx4 c = {};
                c = __builtin_amdgcn_mfma_f32_16x16x32_bf16(kf[nt * 2],     qA0, c, 0, 0, 0);
                c = __builtin_amdgcn_mfma_f32_16x16x32_bf16(kf[nt * 2 + 1], qA1, c, 0, 0, 0);
                aA[nt] = c;
            }
        }
        if (doB) {
#pragma unroll
            for (int nt = 0; nt < 4; ++nt) {
                floatx4 c = {};
                c = __builtin_amdgcn_mfma_f32_16x16x32_bf16(kf[nt * 2],     qB0, c, 0, 0, 0);
                c = __builtin_amdgcn_mfma_f32_16x16x32_bf16(kf[nt * 2 + 1], qB1, c, 0, 0, 0);
                aB[nt] = c;
            }
        }

        if (doA) {
            const bool masked = (kt == nA - 1);
#pragma unroll
            for (int nt = 0; nt < 4; ++nt) {
                union { ushort u[4]; uint2 w; } pk;
#pragma unroll
                for (int r = 0; r < 4; ++r) {
                    float sv = aA[nt][r];
                    if (masked && (k0 + nt * 16 + quad * 4 + r > q0A + l16)) sv = -3.0e38f;
                    float p = __expf(sv);
                    rsA += p;
                    pk.u[r] = f2bf(p);
                }
                *(uint2*)&myPA[l16 * 72 + nt * 16 + quad * 4] = pk.w;
            }
        }
        if (doB) {
            const bool masked = (kt == nB - 1);
#pragma unroll
            for (int nt = 0; nt < 4; ++nt) {
                union { ushort u[4]; uint2 w; } pk;
#pragma unroll
                for (int r = 0; r < 4; ++r) {
                    float sv = aB[nt][r];
                    if (masked && (k0 + nt * 16 + quad * 4 + r > q0B + l16)) sv = -3.0e38f;
                    float p = __expf(sv);
                    rsB += p;
                    pk.u[r] = f2bf(p);
                }
                *(uint2*)&myPB[l16 * 72 + nt * 16 + quad * 4] = pk.w;
            }
        }

        if (doA) {
            short8 p0 = *(const short8*)&myPA[l16 * 72 + quad * 8];
            short8 p1 = *(const short8*)&myPA[l16 * 72 + 32 + quad * 8];
#pragma unroll
            for (int nt = 0; nt < 4; ++nt) {
                OA[nt] = __builtin_amdgcn_mfma_f32_16x16x32_bf16(p0, vf[nt * 2],     OA[nt], 0, 0, 0);
                OA[nt] = __builtin_amdgcn_mfma_f32_16x16x32_bf16(p1, vf[nt * 2 + 1], OA[nt], 0, 0, 0);
            }
        }
        if (doB) {
            short8 p0 = *(const short8*)&myPB[l16 * 72 + quad * 8];
            short8 p1 = *(const short8*)&myPB[l16 * 72 + 32 + quad * 8];
#pragma unroll
            for (int nt = 0; nt < 4; ++nt) {
                OB[nt] = __builtin_amdgcn_mfma_f32_16x16x32_bf16(p0, vf[nt * 2],     OB[nt], 0, 0, 0);
                OB[nt] = __builtin_amdgcn_mfma_f32_16x16x32_bf16(p1, vf[nt * 2 + 1], OB[nt], 0, 0, 0);
            }
        }
    }

    // ---- merge tile A ----
    rsA += __shfl_xor(rsA, 16); rsA += __shfl_xor(rsA, 32);
    if (quad == 0) Lbuf[wv][l16] = rsA;
#pragma unroll
    for (int nt = 0; nt < 4; ++nt)
#pragma unroll
        for (int r = 0; r < 4; ++r)
            Obuf[wv][quad * 4 + r][nt * 16 + l16] = OA[nt][r];
    __syncthreads();
    {
        const int row = tid >> 4, h0 = (tid & 15) * 4;
        float l = Lbuf[0][row] + Lbuf[1][row] + Lbuf[2][row] + Lbuf[3][row];
        float inv = 1.f / l;
        float4 o;
        o.x = (Obuf[0][row][h0+0] + Obuf[1][row][h0+0] + Obuf[2][row][h0+0] + Obuf[3][row][h0+0]) * inv;
        o.y = (Obuf[0][row][h0+1] + Obuf[1][row][h0+1] + Obuf[2][row][h0+1] + Obuf[3][row][h0+1]) * inv;
        o.z = (Obuf[0][row][h0+2] + Obuf[1][row][h0+2] + Obuf[2][row][h0+2] + Obuf[3][row][h0+2]) * inv;
        o.w = (Obuf[0][row][h0+3] + Obuf[1][row][h0+3] + Obuf[2][row][h0+3] + Obuf[3][row][h0+3]) * inv;
        *(float4*)&out[((size_t)b * SEQ + q0A + row) * HEAD + h0] = o;
    }
    __syncthreads();

    // ---- merge tile B ----
    rsB += __shfl_xor(rsB, 16); rsB += __shfl_xor(rsB, 32);
    if (quad == 0) Lbuf[wv][l16] = rsB;
#pragma unroll
    for (int nt = 0; nt < 4; ++nt)
#pragma unroll
        for (int r = 0; r < 4; ++r)
            Obuf[wv][quad * 4 + r][nt * 16 + l16] = OB[nt][r];
    __syncthreads();
    {
        const int row = tid >> 4, h0 = (tid & 15) * 4;
        float l = Lbuf[0][row] + Lbuf[1][row] + Lbuf[2][row] + Lbuf[3][row];
        float inv = 1.f / l;
        float4 o;
        o.x = (Obuf[0][row][h0+0] + Obuf[1][row][h0+0] + Obuf[2][row][h0+0] + Obuf[3][row][h0+0]) * inv;
        o.y = (Obuf[0][row][h0+1] + Obuf[1][row][h0+1] + Obuf[2][row][h0+1] + Obuf[3][row][h0+1]) * inv;
        o.z = (Obuf[0][row][h0+2] + Obuf[1][row][h0+2] + Obuf[2][row][h0+2] + Obuf[3][row][h0+2]) * inv;
        o.w = (Obuf[0][row][h0+3] + Obuf[1][row][h0+3] + Obuf[2][row][h0+3] + Obuf[3][row][h0+3]) * inv;
        *(float4*)&out[((size_t)b * SEQ + q0B + row) * HEAD + h0] = o;
    }
}

// ---------------------------------------------------------------------------
extern "C" void kernel_launch(void* const* d_in, const int* in_sizes, int n_in,
                              void* d_out, int out_size, void* d_ws, size_t ws_size,
                              hipStream_t stream) {
    const float* q  = (const float*)d_in[0];
    const float* k  = (const float*)d_in[1];
    const float* v  = (const float*)d_in[2];
    const float* wq = (const float*)d_in[3];
    const float* wk = (const float*)d_in[4];
    const float* wv = (const float*)d_in[5];

    // ws: qh bf16 (2MB) | kh bf16 (2MB) | vt bf16 [4][64][4096] (2MB) | wt (384KB)
    ushort* qh = (ushort*)d_ws;
    ushort* kh = qh + (size_t)NROWS * HEAD;
    ushort* vt = kh + (size_t)NROWS * HEAD;
    ushort* wt = vt + (size_t)NROWS * HEAD;

    dim3 wgrid(D_MODEL / 64, 3);
    wprep_kernel<<<wgrid, 256, 0, stream>>>(wq, wk, wv, wt);

    dim3 pgrid(NROWS / 64, 3);   // 256 x 3, 4-wave blocks, counted-vmcnt staging
    proj_kernel<<<pgrid, 256, 0, stream>>>(q, k, v, wt, qh, kh, vt);

    attn_kernel<<<BATCH * 128, 256, 0, stream>>>(qh, kh, vt, (float*)d_out);
}

// Round 10
// 248.386 us; speedup vs baseline: 1.6415x; 1.0801x over previous
//
#include <hip/hip_runtime.h>
#include <hip/hip_bf16.h>
#include <cstdint>

#define D_MODEL 1024
#define HEAD    64
#define SEQ     4096
#define BATCH   4
#define NROWS   (BATCH * SEQ)   // 16384

typedef __attribute__((ext_vector_type(8))) short short8;   // 8 bf16 (MFMA A/B frag)
typedef __attribute__((ext_vector_type(4))) float floatx4;  // MFMA C/D frag

__device__ __forceinline__ ushort f2bf(float f) {
    union { __hip_bfloat16 h; ushort u; } c;
    c.h = __float2bfloat16(f);
    return c.u;
}
__device__ __forceinline__ uint pk2(float a, float b) {
    return (uint)f2bf(a) | ((uint)f2bf(b) << 16);
}

// Async global->LDS, 16B per lane, wave-uniform LDS base (+lane*16 implicit).
__device__ __forceinline__ void gload16(const void* g, void* l) {
    __builtin_amdgcn_global_load_lds(
        (const __attribute__((address_space(1))) unsigned int*)g,
        (__attribute__((address_space(3))) unsigned int*)l, 16, 0, 0);
}
// NT (non-temporal, CPol=2) variant: read-once streams bypass/evict-first L2
// so they don't occupy the L2 miss path & don't pollute the cache.
__device__ __forceinline__ void gload16nt(const void* g, void* l) {
    __builtin_amdgcn_global_load_lds(
        (const __attribute__((address_space(1))) unsigned int*)g,
        (__attribute__((address_space(3))) unsigned int*)l, 16, 0, 2);
}

// ---------------------------------------------------------------------------
// wt[which][n][k] = w_which[k][n] bf16, via LDS tile transpose (coalesced both ways).
// Grid (D_MODEL/64, 3), 256 threads.
__global__ __launch_bounds__(256) void wprep_kernel(
    const float* __restrict__ wq, const float* __restrict__ wk,
    const float* __restrict__ wv, ushort* __restrict__ wt)
{
    const int which = blockIdx.y;
    const int k0    = blockIdx.x * 64;
    const float* w  = (which == 0) ? wq : (which == 1) ? wk : wv;
    const int tid   = threadIdx.x;

    __shared__ ushort lds[64][65];

#pragma unroll
    for (int i = 0; i < 16; ++i) {
        int idx = tid + 256 * i;          // 0..4095
        int kl  = idx >> 6;
        int n   = idx & 63;
        lds[n][kl] = f2bf(w[(size_t)(k0 + kl) * 64 + n]);   // coalesced read
    }
    __syncthreads();
#pragma unroll
    for (int i = 0; i < 16; ++i) {
        int idx = tid + 256 * i;
        int n   = idx >> 6;
        int kl  = idx & 63;
        wt[(size_t)(which * 64 + n) * D_MODEL + k0 + kl] = lds[n][kl];  // coalesced write
    }
}

// ---------------------------------------------------------------------------
// proj v7 = R7 frozen structure + ONE change: A-stream DMAs use NT cache
// policy (aux=2). Theory: proj's floor (~80us, 1.2-1.35 TB/s across SIX
// structurally different pipelines) is the per-XCD L2-miss-handling rate --
// the A stream is read-once, all-miss, and clogs MSHRs while polluting L2.
// NT marks it evict-first/streaming. W keeps aux=0 (reused, L2-hot).
// Everything else byte-identical to R7/R9's proj.
__global__ __launch_bounds__(256) void proj_kernel(
    const float* __restrict__ xq, const float* __restrict__ xk,
    const float* __restrict__ xv, const ushort* __restrict__ wt,
    ushort* __restrict__ qh, ushort* __restrict__ kh, ushort* __restrict__ vt)
{
    const int which = blockIdx.y;
    const float*  x = (which == 0) ? xq : (which == 1) ? xk : xv;
    const ushort* w = wt + (size_t)which * 64 * D_MODEL;

    const int row0 = blockIdx.x * 64;
    const int tid  = threadIdx.x;
    const int wv   = tid >> 6;
    const int ln   = tid & 63;
    const int l16  = ln & 15;
    const int quad = ln >> 4;

    __shared__ float  Abuf[2][64 * 64];   // [row][col f32], 256B/row, col-swizzled
    __shared__ ushort Wbuf[2][64 * 64];   // [n][k bf16], 128B/row, col-swizzled

    const float* asrc[4];
#pragma unroll
    for (int i = 0; i < 4; ++i) {
        int j  = wv * 4 + i;
        int lr = 4 * j + (ln >> 4);
        int cf = ((ln & 15) ^ (lr & 15)) * 4;
        asrc[i] = x + (size_t)(row0 + lr) * D_MODEL + cf;
    }
    const ushort* wsrc[2];
#pragma unroll
    for (int i = 0; i < 2; ++i) {
        int j  = wv * 2 + i;
        int n  = 8 * j + (ln >> 3);
        int kc = ((ln & 7) ^ (ln >> 3)) * 8;
        wsrc[i] = w + (size_t)n * D_MODEL + kc;
    }

    floatx4 acc[4] = {};

#define STAGE(buf, kk)                                                        \
    do {                                                                      \
        char* ab_ = (char*)&Abuf[buf][0];                                     \
        char* wb_ = (char*)&Wbuf[buf][0];                                     \
        _Pragma("unroll")                                                     \
        for (int i_ = 0; i_ < 4; ++i_)                                        \
            gload16nt(asrc[i_] + (kk), ab_ + (wv * 4 + i_) * 1024);           \
        _Pragma("unroll")                                                     \
        for (int i_ = 0; i_ < 2; ++i_)                                        \
            gload16(wsrc[i_] + (kk), wb_ + (wv * 2 + i_) * 1024);             \
    } while (0)

#define COMPUTE(buf)                                                          \
    do {                                                                      \
        const char* ab_ = (const char*)&Abuf[buf][0];                         \
        const char* wb_ = (const char*)&Wbuf[buf][0];                         \
        const int arow_ = wv * 16 + l16;                                      \
        const int akey_ = l16 << 4;            /* (arow&15)<<4 */             \
        _Pragma("unroll")                                                     \
        for (int ks_ = 0; ks_ < 2; ++ks_) {                                   \
            const int colb_ = (ks_ * 32 + quad * 8) * 4;                      \
            float4 f0 = *(const float4*)(ab_ + arow_ * 256 + ((colb_)      ^ akey_)); \
            float4 f1 = *(const float4*)(ab_ + arow_ * 256 + ((colb_ + 16) ^ akey_)); \
            union { short8 s; uint u[4]; } a_;                                \
            a_.u[0] = pk2(f0.x, f0.y); a_.u[1] = pk2(f0.z, f0.w);             \
            a_.u[2] = pk2(f1.x, f1.y); a_.u[3] = pk2(f1.z, f1.w);             \
            const int wcolb_ = (ks_ * 32 + quad * 8) * 2;                     \
            const int wkey_  = (l16 & 7) << 4;  /* (n&7)<<4, n=nt*16+l16 */   \
            _Pragma("unroll")                                                 \
            for (int nt_ = 0; nt_ < 4; ++nt_) {                               \
                const int n_ = nt_ * 16 + l16;                                \
                short8 bf_ = *(const short8*)(wb_ + n_ * 128 + (wcolb_ ^ wkey_)); \
                acc[nt_] = __builtin_amdgcn_mfma_f32_16x16x32_bf16(a_.s, bf_, acc[nt_], 0, 0, 0); \
            }                                                                 \
        }                                                                     \
    } while (0)

    STAGE(0, 0);
    STAGE(1, 64);
    for (int t = 0; t < 16; ++t) {
        if (t == 15) {
            asm volatile("s_waitcnt vmcnt(0)" ::: "memory");
        } else {
            asm volatile("s_waitcnt vmcnt(6)" ::: "memory");
        }
        __builtin_amdgcn_sched_barrier(0);
        __builtin_amdgcn_s_barrier();        // all waves' chunk-t parts landed
        __builtin_amdgcn_sched_barrier(0);
        __builtin_amdgcn_s_setprio(1);
        COMPUTE(t & 1);
        __builtin_amdgcn_s_setprio(0);
        __builtin_amdgcn_sched_barrier(0);
        __builtin_amdgcn_s_barrier();        // all waves done READING buf t&1
        __builtin_amdgcn_sched_barrier(0);
        if (t + 2 < 16) STAGE(t & 1, (t + 2) * 64);
    }
#undef STAGE
#undef COMPUTE

    const int rbase = row0 + wv * 16 + quad * 4;
    if (which < 2) {
        ushort* y = (which == 0) ? qh : kh;
        const float sc = (which == 0) ? 0.125f : 1.0f;   // fold head^-0.5 into qh
#pragma unroll
        for (int nt = 0; nt < 4; ++nt) {
            int h = nt * 16 + l16;
#pragma unroll
            for (int r = 0; r < 4; ++r)
                y[(size_t)(rbase + r) * HEAD + h] = f2bf(acc[nt][r] * sc);
        }
    } else {
        const int b  = rbase >> 12;
        const int s0 = rbase & (SEQ - 1);
#pragma unroll
        for (int nt = 0; nt < 4; ++nt) {
            int h = nt * 16 + l16;
            uint2 pk = make_uint2(pk2(acc[nt][0], acc[nt][1]), pk2(acc[nt][2], acc[nt][3]));
            *(uint2*)&vt[(size_t)(b * 64 + h) * SEQ + s0] = pk;
        }
    }
}

// ---------------------------------------------------------------------------
// MFMA flash attention (R9, best measured): paired q-tiles, shared K/V
// fragments (one load feeds both chains -- R9 win), 4-wave K-split,
// max-free softmax, (O,l) additive merge. Do not cap launch_bounds higher
// (R8's (384,3) spilled 418MB to scratch).
__global__ __launch_bounds__(256, 2) void attn_kernel(
    const ushort* __restrict__ qh, const ushort* __restrict__ kh,
    const ushort* __restrict__ vt, float* __restrict__ out)
{
    const int b    = blockIdx.x >> 7;          // 4 batches x 128 tile-pairs
    const int i    = blockIdx.x & 127;
    const int qsA  = i, qsB = 255 - i;
    const int q0A  = qsA * 16, q0B = qsB * 16;
    const int nA   = (qsA >> 2) + 1;           // key tiles for tile A
    const int nB   = (qsB >> 2) + 1;
    const int tid  = threadIdx.x;
    const int wv   = tid >> 6;
    const int ln   = tid & 63;
    const int l16  = ln & 15;
    const int quad = ln >> 4;

    __shared__ ushort PA[4][16 * 72];
    __shared__ ushort PB[4][16 * 72];
    __shared__ float  Obuf[4][16][68];
    __shared__ float  Lbuf[4][16];

    const ushort* khb = kh + (size_t)b * SEQ * HEAD;
    const ushort* vtb = vt + (size_t)b * HEAD * SEQ;

    // Q B-frags (pre-scaled): n = l16 -> qrow, k = quad*8+j -> h
    const size_t qbA = ((size_t)b * SEQ + q0A + l16) * HEAD + quad * 8;
    const size_t qbB = ((size_t)b * SEQ + q0B + l16) * HEAD + quad * 8;
    const short8 qA0 = *(const short8*)(qh + qbA);
    const short8 qA1 = *(const short8*)(qh + qbA + 32);
    const short8 qB0 = *(const short8*)(qh + qbB);
    const short8 qB1 = *(const short8*)(qh + qbB + 32);

    floatx4 OA[4] = {}, OB[4] = {};
    float rsA = 0.f, rsB = 0.f;
    ushort* myPA = PA[wv];
    ushort* myPB = PB[wv];

    const int cA = (nA > wv) ? (((nA - 1 - wv) >> 2) + 1) : 0;   // steps for A
    const int cB = ((nB - 1 - wv) >> 2) + 1;                     // nB >= 33 > wv
    const int steps = (cA > cB) ? cA : cB;                       // == cB (cA<=cB)

    for (int s = 0; s < steps; ++s) {
        const int kt = wv + 4 * s;                 // SAME tile for A and B
        const bool doA = s < cA, doB = s < cB;
        const int k0 = kt * 64;

        // ---- shared K/V fragments (one load feeds both chains) ----
        short8 kf[8], vf[8];
        if (doA || doB) {
#pragma unroll
            for (int nt = 0; nt < 4; ++nt) {
                const ushort* vp = vtb + (size_t)(nt * 16 + l16) * SEQ + k0 + quad * 8;
                vf[nt * 2] = *(const short8*)vp; vf[nt * 2 + 1] = *(const short8*)(vp + 32);
                const ushort* kp = khb + (size_t)(k0 + nt * 16 + l16) * HEAD + quad * 8;
                kf[nt * 2] = *(const short8*)kp; kf[nt * 2 + 1] = *(const short8*)(kp + 32);
            }
        }

        // S^T = K Q^T : C row = key (quad*4+r), col = qrow (l16)
        floatx4 aA[4], aB[4];
        if (doA) {
#pragma unroll
            for (int nt = 0; nt < 4; ++nt) {
                floatx4 c = {};
                c = __builtin_amdgcn_mfma_f32_16x16x32_bf16(kf[nt * 2],     qA0, c, 0, 0, 0);
                c = __builtin_amdgcn_mfma_f32_16x16x32_bf16(kf[nt * 2 + 1], qA1, c, 0, 0, 0);
                aA[nt] = c;
            }
        }
        if (doB) {
#pragma unroll
            for (int nt = 0; nt < 4; ++nt) {
                floatx4 c = {};
                c = __builtin_amdgcn_mfma_f32_16x16x32_bf16(kf[nt * 2],     qB0, c, 0, 0, 0);
                c = __builtin_amdgcn_mfma_f32_16x16x32_bf16(kf[nt * 2 + 1], qB1, c, 0, 0, 0);
                aB[nt] = c;
            }
        }

        if (doA) {
            const bool masked = (kt == nA - 1);
#pragma unroll
            for (int nt = 0; nt < 4; ++nt) {
                union { ushort u[4]; uint2 w; } pk;
#pragma unroll
                for (int r = 0; r < 4; ++r) {
                    float sv = aA[nt][r];
                    if (masked && (k0 + nt * 16 + quad * 4 + r > q0A + l16)) sv = -3.0e38f;
                    float p = __expf(sv);
                    rsA += p;
                    pk.u[r] = f2bf(p);
                }
                *(uint2*)&myPA[l16 * 72 + nt * 16 + quad * 4] = pk.w;
            }
        }
        if (doB) {
            const bool masked = (kt == nB - 1);
#pragma unroll
            for (int nt = 0; nt < 4; ++nt) {
                union { ushort u[4]; uint2 w; } pk;
#pragma unroll
                for (int r = 0; r < 4; ++r) {
                    float sv = aB[nt][r];
                    if (masked && (k0 + nt * 16 + quad * 4 + r > q0B + l16)) sv = -3.0e38f;
                    float p = __expf(sv);
                    rsB += p;
                    pk.u[r] = f2bf(p);
                }
                *(uint2*)&myPB[l16 * 72 + nt * 16 + quad * 4] = pk.w;
            }
        }

        if (doA) {
            short8 p0 = *(const short8*)&myPA[l16 * 72 + quad * 8];
            short8 p1 = *(const short8*)&myPA[l16 * 72 + 32 + quad * 8];
#pragma unroll
            for (int nt = 0; nt < 4; ++nt) {
                OA[nt] = __builtin_amdgcn_mfma_f32_16x16x32_bf16(p0, vf[nt * 2],     OA[nt], 0, 0, 0);
                OA[nt] = __builtin_amdgcn_mfma_f32_16x16x32_bf16(p1, vf[nt * 2 + 1], OA[nt], 0, 0, 0);
            }
        }
        if (doB) {
            short8 p0 = *(const short8*)&myPB[l16 * 72 + quad * 8];
            short8 p1 = *(const short8*)&myPB[l16 * 72 + 32 + quad * 8];
#pragma unroll
            for (int nt = 0; nt < 4; ++nt) {
                OB[nt] = __builtin_amdgcn_mfma_f32_16x16x32_bf16(p0, vf[nt * 2],     OB[nt], 0, 0, 0);
                OB[nt] = __builtin_amdgcn_mfma_f32_16x16x32_bf16(p1, vf[nt * 2 + 1], OB[nt], 0, 0, 0);
            }
        }
    }

    // ---- merge tile A ----
    rsA += __shfl_xor(rsA, 16); rsA += __shfl_xor(rsA, 32);
    if (quad == 0) Lbuf[wv][l16] = rsA;
#pragma unroll
    for (int nt = 0; nt < 4; ++nt)
#pragma unroll
        for (int r = 0; r < 4; ++r)
            Obuf[wv][quad * 4 + r][nt * 16 + l16] = OA[nt][r];
    __syncthreads();
    {
        const int row = tid >> 4, h0 = (tid & 15) * 4;
        float l = Lbuf[0][row] + Lbuf[1][row] + Lbuf[2][row] + Lbuf[3][row];
        float inv = 1.f / l;
        float4 o;
        o.x = (Obuf[0][row][h0+0] + Obuf[1][row][h0+0] + Obuf[2][row][h0+0] + Obuf[3][row][h0+0]) * inv;
        o.y = (Obuf[0][row][h0+1] + Obuf[1][row][h0+1] + Obuf[2][row][h0+1] + Obuf[3][row][h0+1]) * inv;
        o.z = (Obuf[0][row][h0+2] + Obuf[1][row][h0+2] + Obuf[2][row][h0+2] + Obuf[3][row][h0+2]) * inv;
        o.w = (Obuf[0][row][h0+3] + Obuf[1][row][h0+3] + Obuf[2][row][h0+3] + Obuf[3][row][h0+3]) * inv;
        *(float4*)&out[((size_t)b * SEQ + q0A + row) * HEAD + h0] = o;
    }
    __syncthreads();

    // ---- merge tile B ----
    rsB += __shfl_xor(rsB, 16); rsB += __shfl_xor(rsB, 32);
    if (quad == 0) Lbuf[wv][l16] = rsB;
#pragma unroll
    for (int nt = 0; nt < 4; ++nt)
#pragma unroll
        for (int r = 0; r < 4; ++r)
            Obuf[wv][quad * 4 + r][nt * 16 + l16] = OB[nt][r];
    __syncthreads();
    {
        const int row = tid >> 4, h0 = (tid & 15) * 4;
        float l = Lbuf[0][row] + Lbuf[1][row] + Lbuf[2][row] + Lbuf[3][row];
        float inv = 1.f / l;
        float4 o;
        o.x = (Obuf[0][row][h0+0] + Obuf[1][row][h0+0] + Obuf[2][row][h0+0] + Obuf[3][row][h0+0]) * inv;
        o.y = (Obuf[0][row][h0+1] + Obuf[1][row][h0+1] + Obuf[2][row][h0+1] + Obuf[3][row][h0+1]) * inv;
        o.z = (Obuf[0][row][h0+2] + Obuf[1][row][h0+2] + Obuf[2][row][h0+2] + Obuf[3][row][h0+2]) * inv;
        o.w = (Obuf[0][row][h0+3] + Obuf[1][row][h0+3] + Obuf[2][row][h0+3] + Obuf[3][row][h0+3]) * inv;
        *(float4*)&out[((size_t)b * SEQ + q0B + row) * HEAD + h0] = o;
    }
}

// ---------------------------------------------------------------------------
extern "C" void kernel_launch(void* const* d_in, const int* in_sizes, int n_in,
                              void* d_out, int out_size, void* d_ws, size_t ws_size,
                              hipStream_t stream) {
    const float* q  = (const float*)d_in[0];
    const float* k  = (const float*)d_in[1];
    const float* v  = (const float*)d_in[2];
    const float* wq = (const float*)d_in[3];
    const float* wk = (const float*)d_in[4];
    const float* wv = (const float*)d_in[5];

    // ws: qh bf16 (2MB) | kh bf16 (2MB) | vt bf16 [4][64][4096] (2MB) | wt (384KB)
    ushort* qh = (ushort*)d_ws;
    ushort* kh = qh + (size_t)NROWS * HEAD;
    ushort* vt = kh + (size_t)NROWS * HEAD;
    ushort* wt = vt + (size_t)NROWS * HEAD;

    dim3 wgrid(D_MODEL / 64, 3);
    wprep_kernel<<<wgrid, 256, 0, stream>>>(wq, wk, wv, wt);

    dim3 pgrid(NROWS / 64, 3);   // 256 x 3, 4-wave blocks, counted-vmcnt + NT A-stream
    proj_kernel<<<pgrid, 256, 0, stream>>>(q, k, v, wt, qh, kh, vt);

    attn_kernel<<<BATCH * 128, 256, 0, stream>>>(qh, kh, vt, (float*)d_out);
}